// Round 6
// baseline (270.321 us; speedup 1.0000x reference)
//
#include <hip/hip_runtime.h>
#include <hip/hip_bf16.h>

#define BB 8
#define CC 512
#define NN 4096
#define CQ 64

typedef __bf16 bf16;
typedef __bf16 bf16x4 __attribute__((ext_vector_type(4)));
typedef __bf16 bf16x8 __attribute__((ext_vector_type(8)));
typedef float f32x4 __attribute__((ext_vector_type(4)));

__device__ __forceinline__ f32x4 mfma16(bf16x8 a, bf16x8 b, f32x4 c) {
    return __builtin_amdgcn_mfma_f32_16x16x32_bf16(a, b, c, 0, 0, 0);
}

// All MFMA operands live in [16 rows][32 cols] bf16 micro-tiles (1KB).
// Fragment load: per-lane elem offset l15*32 + lq*8 -> contiguous permuted
// 1024B per wave instruction.
// Tile grids:
//   xTt [B][N/16][C/32]   Wqt/Wkt [CQ/16=4][C/32=16]   Wvt [C/16=32][C/32]
//   Qt/Kt [B][N/16=256][CQ/32=2]            Vt [B][C/16=32][N/32=128]

// ---------------------------------------------------------------------------
// x [B][C][N] f32 -> xTt tiled bf16
// ---------------------------------------------------------------------------
__global__ __launch_bounds__(256) void k_transpose(const float* __restrict__ x,
                                                   bf16* __restrict__ xTt) {
    __shared__ float tile[64][65];
    const int b  = blockIdx.z;
    const int c0 = blockIdx.y * 64;
    const int n0 = blockIdx.x * 64;
    const int t  = threadIdx.x;

    const float* xp = x + ((size_t)b * CC + c0) * NN + n0;
#pragma unroll
    for (int r = 0; r < 16; ++r) {
        int c = r * 4 + (t >> 6);
        int n = t & 63;
        tile[c][n] = xp[(size_t)c * NN + n];
    }
    __syncthreads();
#pragma unroll
    for (int r = 0; r < 16; ++r) {
        int nl = r * 4 + (t >> 6);
        int cl = t & 63;
        size_t off = ((size_t)(b * 256 + (n0 >> 4) + (nl >> 4)) * 16 + (c0 >> 5) + (cl >> 5)) * 512
                   + (nl & 15) * 32 + (cl & 31);
        xTt[off] = (bf16)tile[cl][nl];
    }
}

// ---------------------------------------------------------------------------
// weights f32 [D][C] -> tiled bf16
// ---------------------------------------------------------------------------
__global__ __launch_bounds__(256) void k_castw(const float* __restrict__ Wq,
                                               const float* __restrict__ Wk,
                                               const float* __restrict__ Wv,
                                               bf16* __restrict__ Wqt,
                                               bf16* __restrict__ Wkt,
                                               bf16* __restrict__ Wvt) {
    int i = blockIdx.x * 256 + threadIdx.x;
    const int nqk = CQ * CC;           // 32768
    const float* src;
    bf16* dst;
    int j;
    if (i < nqk) {
        src = Wq; dst = Wqt; j = i;
    } else if (i < 2 * nqk) {
        src = Wk; dst = Wkt; j = i - nqk;
    } else if (i < 2 * nqk + CC * CC) {
        src = Wv; dst = Wvt; j = i - 2 * nqk;
    } else {
        return;
    }
    int d = j >> 9;          // /512
    int c = j & 511;
    size_t off = ((size_t)(d >> 4) * 16 + (c >> 5)) * 512 + (d & 15) * 32 + (c & 31);
    dst[off] = (bf16)src[j];
}

// ---------------------------------------------------------------------------
// Qt/Kt = (xTt) x (W)^T + bias   (tiled in, tiled out)
// ---------------------------------------------------------------------------
__global__ __launch_bounds__(256) void k_proj_qk(const bf16* __restrict__ xTt,
                                                 const bf16* __restrict__ Wqt,
                                                 const bf16* __restrict__ Wkt,
                                                 const float* __restrict__ bq,
                                                 const float* __restrict__ bk,
                                                 bf16* __restrict__ qTt,
                                                 bf16* __restrict__ kTt) {
    const bf16*  Wt   = (blockIdx.z == 0) ? Wqt : Wkt;
    const float* bias = (blockIdx.z == 0) ? bq : bk;
    bf16*        outp = (blockIdx.z == 0) ? qTt : kTt;

    const int b  = blockIdx.y;
    const int nt = blockIdx.x * 4;     // n-tile base
    const int t  = threadIdx.x;
    const int w  = t >> 6;
    const int l  = t & 63;
    const int l15 = l & 15, lq = l >> 4;
    const int loff = l15 * 32 + lq * 8;

    f32x4 acc[4];
#pragma unroll
    for (int dt = 0; dt < 4; ++dt) {
        float bv = bias[dt * 16 + l15];
        acc[dt] = (f32x4){bv, bv, bv, bv};
    }

    const bf16* ap = xTt + ((size_t)(b * 256 + nt + w) * 16) * 512 + loff;
#pragma unroll 4
    for (int ct = 0; ct < 16; ++ct) {              // c-tile (32 wide)
        bf16x8 a = *(const bf16x8*)(ap + (size_t)ct * 512);
#pragma unroll
        for (int dt = 0; dt < 4; ++dt) {
            bf16x8 bfr = *(const bf16x8*)(Wt + ((size_t)dt * 16 + ct) * 512 + loff);
            acc[dt] = mfma16(a, bfr, acc[dt]);
        }
    }
#pragma unroll
    for (int dt = 0; dt < 4; ++dt) {
#pragma unroll
        for (int r = 0; r < 4; ++r) {
            size_t off = ((size_t)(b * 256 + nt + w) * 2 + (dt >> 1)) * 512
                       + (lq * 4 + r) * 32 + (dt & 1) * 16 + l15;
            outp[off] = (bf16)acc[dt][r];
        }
    }
}

// ---------------------------------------------------------------------------
// Vt = Wv x x + bv   (tiled in, tiled out)
// ---------------------------------------------------------------------------
__global__ __launch_bounds__(256) void k_proj_v(const bf16* __restrict__ xTt,
                                                const bf16* __restrict__ Wvt,
                                                const float* __restrict__ bv,
                                                bf16* __restrict__ vt) {
    const int b  = blockIdx.z;
    const int dt0 = blockIdx.y * 4;    // d-tile base (16 wide)
    const int nt0 = blockIdx.x * 4;    // n-tile base (16 wide)
    const int t  = threadIdx.x;
    const int w  = t >> 6;
    const int l  = t & 63;
    const int l15 = l & 15, lq = l >> 4;
    const int loff = l15 * 32 + lq * 8;

    f32x4 acc[4];
    {
        f32x4 binit;
#pragma unroll
        for (int r = 0; r < 4; ++r) binit[r] = bv[(dt0 + w) * 16 + lq * 4 + r];
#pragma unroll
        for (int nt = 0; nt < 4; ++nt) acc[nt] = binit;
    }

    const bf16* ap = Wvt + ((size_t)(dt0 + w) * 16) * 512 + loff;
    const bf16* bp = xTt + ((size_t)(b * 256 + nt0) * 16) * 512 + loff;
#pragma unroll 4
    for (int ct = 0; ct < 16; ++ct) {
        bf16x8 a = *(const bf16x8*)(ap + (size_t)ct * 512);
#pragma unroll
        for (int nt = 0; nt < 4; ++nt) {
            bf16x8 bfr = *(const bf16x8*)(bp + ((size_t)nt * 16 + ct) * 512);
            acc[nt] = mfma16(a, bfr, acc[nt]);
        }
    }
#pragma unroll
    for (int nt = 0; nt < 4; ++nt) {
#pragma unroll
        for (int r = 0; r < 4; ++r) {
            size_t off = ((size_t)(b * 32 + dt0 + w) * 128 + (nt0 >> 1) + (nt >> 1)) * 512
                       + (lq * 4 + r) * 32 + (nt & 1) * 16 + l15;
            vt[off] = (bf16)acc[nt][r];
        }
    }
}

// ---------------------------------------------------------------------------
// Flash attention + epilogue, 1-step software pipeline.
// BM=128, 8 waves, 256 blocks (1/CU, b = bid&7 pins batch V to one XCD L2).
// Body at step jb (straight-line, ONE barrier at end):
//   read P(jb) frags from buf | issue V(jb+1) | QK^T(jb+1) | issue K(jb+2)
//   | softmax(jb+1) -> P-write buf^1 | PV(jb) 32 MFMA
// The softmax VALU/exp of step jb+1 schedules into PV(jb)'s MFMA shadow,
// so the matrix pipe stays fed across the whole body.
// ---------------------------------------------------------------------------
__global__ __launch_bounds__(512, 2) void k_attn(const bf16* __restrict__ qTt,
                                                 const bf16* __restrict__ kTt,
                                                 const bf16* __restrict__ vt,
                                                 const float* __restrict__ x,
                                                 const float* __restrict__ gamma,
                                                 float* __restrict__ out) {
    __shared__ bf16  Pl[2][8][512];    // [buf][it][g*128 + l15*8 + u]
    __shared__ float Ll[128];

    const int b  = blockIdx.x & 7;
    const int i0 = (blockIdx.x >> 3) * 128;
    const int t  = threadIdx.x;
    const int w  = t >> 6;
    const int l  = t & 63;
    const int l15 = l & 15, lq = l >> 4;
    const int loff = l15 * 32 + lq * 8;

    const f32x4 zero4 = {0.f, 0.f, 0.f, 0.f};

    const bf16* kb = kTt + (size_t)b * 256 * 2 * 512 + loff;   // K tiles, lane-offset folded
    const bf16* qb = qTt + (size_t)b * 256 * 2 * 512;
    const bf16* vb = vt + ((size_t)b * 32 + w * 4) * 128 * 512 + loff;

    // Q B-frags for this wave's S^T strip
    bf16x8 qa0, qa1;
    {
        const bf16* qp = qb + ((size_t)((i0 >> 4) + w) * 2) * 512 + loff;
        qa0 = *(const bf16x8*)qp;
        qa1 = *(const bf16x8*)(qp + 512);
    }

    f32x4 acc[4][8];   // [c-tile][i-tile]
#pragma unroll
    for (int ct = 0; ct < 4; ++ct)
#pragma unroll
        for (int it = 0; it < 8; ++it) acc[ct][it] = zero4;
    float lsum = 0.f;

    // ---- prologue: K(0) -> QK^T(0) -> softmax(0) -> P(0)@buf0; V(0), K(1) ----
    bf16x8 kc[4];
#pragma unroll
    for (int q = 0; q < 4; ++q) kc[q] = *(const bf16x8*)(kb + (size_t)q * 512);

    {
        f32x4 s0 = mfma16(kc[0], qa0, zero4); s0 = mfma16(kc[1], qa1, s0);
        f32x4 s1 = mfma16(kc[2], qa0, zero4); s1 = mfma16(kc[3], qa1, s1);
        bf16* Pw0 = &Pl[0][0][0];
        float rs = 0.f;
        {
            float p0 = __expf(s0[0]), p1 = __expf(s0[1]), p2 = __expf(s0[2]), p3 = __expf(s0[3]);
            rs += (p0 + p1) + (p2 + p3);
            bf16x4 pk = {(bf16)p0, (bf16)p1, (bf16)p2, (bf16)p3};
            *(bf16x4*)&Pw0[(size_t)w * 512 + (lq >> 1) * 128 + l15 * 8 + (lq & 1) * 4] = pk;
        }
        {
            float p0 = __expf(s1[0]), p1 = __expf(s1[1]), p2 = __expf(s1[2]), p3 = __expf(s1[3]);
            rs += (p0 + p1) + (p2 + p3);
            bf16x4 pk = {(bf16)p0, (bf16)p1, (bf16)p2, (bf16)p3};
            *(bf16x4*)&Pw0[(size_t)w * 512 + (2 + (lq >> 1)) * 128 + l15 * 8 + (lq & 1) * 4] = pk;
        }
        rs += __shfl_xor(rs, 16);
        rs += __shfl_xor(rs, 32);
        lsum += rs;
    }

    bf16x8 va[4];
#pragma unroll
    for (int ct = 0; ct < 4; ++ct)
        va[ct] = *(const bf16x8*)(vb + ((size_t)ct * 128) * 512);

#pragma unroll
    for (int q = 0; q < 4; ++q) kc[q] = *(const bf16x8*)(kb + (size_t)(4 + q) * 512);

    __syncthreads();

    // ---- main loop ----
#pragma unroll 1
    for (int jb = 0; jb < NN / 32; ++jb) {
        bf16* Pr  = &Pl[jb & 1][0][0];
        bf16* Pwn = &Pl[(jb & 1) ^ 1][0][0];

        // P(jb) first fragment
        bf16x8 pcur = *(const bf16x8*)(Pr + l * 8);

        // V(jb+1) issue
        bf16x8 vn[4];
        {
            const int jv = (jb + 1) & (NN / 32 - 1);
#pragma unroll
            for (int ct = 0; ct < 4; ++ct)
                vn[ct] = *(const bf16x8*)(vb + ((size_t)ct * 128 + jv) * 512);
        }

        // QK^T(jb+1) from kc = K(jb+1)
        f32x4 s0 = mfma16(kc[0], qa0, zero4); s0 = mfma16(kc[1], qa1, s0);
        f32x4 s1 = mfma16(kc[2], qa0, zero4); s1 = mfma16(kc[3], qa1, s1);

        // K(jb+2) issue into kc
        {
            const int jk = (jb + 2) & (NN / 32 - 1);
#pragma unroll
            for (int q = 0; q < 4; ++q)
                kc[q] = *(const bf16x8*)(kb + (size_t)(jk * 4 + q) * 512);
        }

        // softmax(jb+1) -> P-write to buf^1 (interleaves with PV below)
        float rs = 0.f;
        {
            float p0 = __expf(s0[0]), p1 = __expf(s0[1]), p2 = __expf(s0[2]), p3 = __expf(s0[3]);
            rs += (p0 + p1) + (p2 + p3);
            bf16x4 pk = {(bf16)p0, (bf16)p1, (bf16)p2, (bf16)p3};
            *(bf16x4*)&Pwn[(size_t)w * 512 + (lq >> 1) * 128 + l15 * 8 + (lq & 1) * 4] = pk;
        }
        {
            float p0 = __expf(s1[0]), p1 = __expf(s1[1]), p2 = __expf(s1[2]), p3 = __expf(s1[3]);
            rs += (p0 + p1) + (p2 + p3);
            bf16x4 pk = {(bf16)p0, (bf16)p1, (bf16)p2, (bf16)p3};
            *(bf16x4*)&Pwn[(size_t)w * 512 + (2 + (lq >> 1)) * 128 + l15 * 8 + (lq & 1) * 4] = pk;
        }
        rs += __shfl_xor(rs, 16);
        rs += __shfl_xor(rs, 32);
        if (jb != NN / 32 - 1) lsum += rs;

        // PV(jb): pb pipelined one fragment ahead (2 live)
#pragma unroll
        for (int it = 0; it < 8; ++it) {
            bf16x8 pnext;
            if (it < 7) pnext = *(const bf16x8*)(Pr + (size_t)(it + 1) * 512 + l * 8);
            acc[0][it] = mfma16(va[0], pcur, acc[0][it]);
            acc[1][it] = mfma16(va[1], pcur, acc[1][it]);
            acc[2][it] = mfma16(va[2], pcur, acc[2][it]);
            acc[3][it] = mfma16(va[3], pcur, acc[3][it]);
            pcur = pnext;
        }

        __syncthreads();
#pragma unroll
        for (int ct = 0; ct < 4; ++ct) va[ct] = vn[ct];
    }

    // share row sums across waves
    if (l < 16) Ll[w * 16 + l] = lsum;
    __syncthreads();

    // ---- epilogue: out = gamma * O / l + x ----
    const float g = gamma[0];
    float linv[8];
#pragma unroll
    for (int it = 0; it < 8; ++it) linv[it] = 1.0f / Ll[it * 16 + l15];

#pragma unroll
    for (int ct = 0; ct < 4; ++ct) {
#pragma unroll
        for (int it = 0; it < 8; ++it) {
#pragma unroll
            for (int r = 0; r < 4; ++r) {
                int c = w * 64 + ct * 16 + lq * 4 + r;
                size_t idx = ((size_t)b * CC + c) * NN + i0 + it * 16 + l15;
                out[idx] = g * (acc[ct][it][r] * linv[it]) + x[idx];
            }
        }
    }
}

// ---------------------------------------------------------------------------
extern "C" void kernel_launch(void* const* d_in, const int* in_sizes, int n_in,
                              void* d_out, int out_size, void* d_ws, size_t ws_size,
                              hipStream_t stream) {
    const float* x     = (const float*)d_in[0];
    const float* Wq    = (const float*)d_in[1];
    const float* bq    = (const float*)d_in[2];
    const float* Wk    = (const float*)d_in[3];
    const float* bk    = (const float*)d_in[4];
    const float* Wv    = (const float*)d_in[5];
    const float* bv    = (const float*)d_in[6];
    const float* gamma = (const float*)d_in[7];
    float* out = (float*)d_out;

    char* p = (char*)d_ws;
    bf16* xTt = (bf16*)p; p += (size_t)BB * NN * CC * sizeof(bf16);
    bf16* qTt = (bf16*)p; p += (size_t)BB * NN * CQ * sizeof(bf16);
    bf16* kTt = (bf16*)p; p += (size_t)BB * NN * CQ * sizeof(bf16);
    bf16* vt  = (bf16*)p; p += (size_t)BB * CC * NN * sizeof(bf16);
    bf16* Wqt = (bf16*)p; p += (size_t)CQ * CC * sizeof(bf16);
    bf16* Wkt = (bf16*)p; p += (size_t)CQ * CC * sizeof(bf16);
    bf16* Wvt = (bf16*)p; p += (size_t)CC * CC * sizeof(bf16);

    k_transpose<<<dim3(NN / 64, CC / 64, BB), 256, 0, stream>>>(x, xTt);
    k_castw<<<(2 * CQ * CC + CC * CC + 255) / 256, 256, 0, stream>>>(Wq, Wk, Wv, Wqt, Wkt, Wvt);
    k_proj_qk<<<dim3(NN / 64, BB, 2), 256, 0, stream>>>(xTt, Wqt, Wkt, bq, bk, qTt, kTt);
    k_proj_v<<<dim3(NN / 64, CC / 64, BB), 256, 0, stream>>>(xTt, Wvt, bv, vt);
    k_attn<<<256, 512, 0, stream>>>(qTt, kTt, vt, x, gamma, out);
}